// Round 11
// baseline (135.205 us; speedup 1.0000x reference)
//
#include <hip/hip_runtime.h>

#define BATCH 32
#define HH 1024
#define WW 1024
#define NPIX (HH * WW)
#define NEROS 10
#define TPS 64                // 16-row tiles per sample (tail kernel)
#define NTILES (BATCH * TPS)  // 2048 (tail grid)
#define NB0 (BATCH * 128)     // conv0: 4096 blocks, 8-row x 1024-px bands
#define FRPS 1024             // flag uints per sample: one uint per row

// Flag uint per row: byte seg (0..3) covers px [256*seg, 256*seg+256); bit c
// (0..3) of that byte = 64-px chunk (seg*4+c) has a nonzero. Unflagged chunks
// are exact zeros: never written, never read. For chunk k (0..15) the uint
// bit position is 8*(k>>2) + (k&3).

__device__ __forceinline__ float4 ld4f(const float* p) {
    return *reinterpret_cast<const float4*>(p);
}

// ---------------- iteration 0: barrier-free per-wave rolling pipeline -------
// Block = 8-row x 1024-px band, 4 waves; wave w independently owns the
// 8-row x 256-px strip at px [256w, 256w+256). 3-slot register ring: issue
// row y+2's pred/tgt quads (+ lane-0/63 edge scalars) before consuming row
// y+1 and computing row y -> ~2 rows x 2 arrays in flight per wave, no
// barriers until the end-of-block reduce. Chunk-sparse stores; flags are
// owned byte stores (no atomics).
__global__ __launch_bounds__(256, 6) void conv0_kernel(
    const float* __restrict__ pred, const float* __restrict__ tgt,
    float* __restrict__ out, unsigned* __restrict__ Fout,
    unsigned* __restrict__ cntOut, unsigned* __restrict__ omin,
    unsigned* __restrict__ omax, double* __restrict__ osum) {
    int blk = blockIdx.x;
    blk = (blk & 7) * (NB0 >> 3) + (blk >> 3);  // XCD swizzle (4096%8==0)
    const int s = blk >> 7, band = blk & 127;
    const int y0 = band << 3;
    const int tid = threadIdx.x, lane = tid & 63, w = tid >> 6;  // w: 0..3
    const int xb = (w << 8) + (lane << 2);
    const size_t sbase = (size_t)s * NPIX;
    unsigned char* Fb = (unsigned char*)Fout;

    float4 pS[3], tS[3];
    float peS[3], teS[3];

    auto issue = [&](int yy, int sl) {
        if (yy >= 0 && yy < HH) {
            const size_t g = sbase + (size_t)yy * WW + xb;
            pS[sl] = ld4f(pred + g);
            tS[sl] = ld4f(tgt + g);
            float pe = 0.f, te = 0.f;
            if (lane == 0) {
                if (xb > 0) { pe = pred[g - 1]; te = tgt[g - 1]; }
            } else if (lane == 63) {
                if (xb + 4 < WW) { pe = pred[g + 4]; te = tgt[g + 4]; }
            }
            peS[sl] = pe;
            teS[sl] = te;
        } else {
            pS[sl] = make_float4(0.f, 0.f, 0.f, 0.f);
            tS[sl] = make_float4(0.f, 0.f, 0.f, 0.f);
            peS[sl] = 0.f;
            teS[sl] = 0.f;
        }
    };
    auto mk = [&](int sl, float* b, float& e) {
        b[0] = (pS[sl].x - tS[sl].x) * (pS[sl].x - tS[sl].x);
        b[1] = (pS[sl].y - tS[sl].y) * (pS[sl].y - tS[sl].y);
        b[2] = (pS[sl].z - tS[sl].z) * (pS[sl].z - tS[sl].z);
        b[3] = (pS[sl].w - tS[sl].w) * (pS[sl].w - tS[sl].w);
        const float d = peS[sl] - teS[sl];
        e = d * d;
    };

    issue(y0 - 1, 0);
    issue(y0, 1);
    issue(y0 + 1, 2);

    float bA[4], bB[4], bC[4], eA, eB, eC;
    mk(0, bA, eA);
    mk(1, bB, eB);

    float lmin = 3.4e38f, lmax = 0.f, lsum = 0.f;
    unsigned any = 0u;

#pragma unroll
    for (int r = 0; r < 8; ++r) {
        if (r < 7) issue(y0 + 2 + r, r % 3);   // keep pipeline 2 rows ahead
        mk((r + 2) % 3, bC, eC);               // row y0+1+r
        const int y = y0 + r;

        float lf = __shfl_up(bB[3], 1);
        if (lane == 0) lf = eB;  // bound(y, xb-1), 0 at image edge
        float rt = __shfl_down(bB[0], 1);
        if (lane == 63) rt = eB;  // bound(y, xb+4), 0 at image edge
        const float lv[4] = {lf, bB[0], bB[1], bB[2]};
        const float rv[4] = {bB[1], bB[2], bB[3], rt};

        float O[4];
        bool nz = false;
#pragma unroll
        for (int j = 0; j < 4; ++j) {
            const float conv =
                0.2f * (bA[j] + bC[j] + bB[j] + lv[j] + rv[j]);
            const float er = fmaxf(conv - 0.5f, 0.f);
            O[j] = er;
            lmin = fminf(lmin, er);
            lmax = fmaxf(lmax, er);
            lsum += er;
            nz = nz || (er > 0.f);
        }
        const unsigned long long bal = __ballot(nz);
        // store lane's quad iff its 64-px chunk (16-lane group) has a nonzero
        if ((bal >> ((lane >> 4) << 4)) & 0xFFFFull)
            *reinterpret_cast<float4*>(out + sbase + (size_t)y * WW + xb) =
                make_float4(O[0], O[1], O[2], O[3]);
        unsigned rb = 0u;
        if (bal & 0xFFFFull) rb |= 1u;
        if ((bal >> 16) & 0xFFFFull) rb |= 2u;
        if ((bal >> 32) & 0xFFFFull) rb |= 4u;
        if ((bal >> 48) & 0xFFFFull) rb |= 8u;
        if (lane == 0)
            Fb[(((unsigned)(s << 10) + y) << 2) + w] = (unsigned char)rb;
        any |= rb;

#pragma unroll
        for (int j = 0; j < 4; ++j) { bA[j] = bB[j]; bB[j] = bC[j]; }
        eB = eC;
    }

    // ---- end-of-block reduce ----
#pragma unroll
    for (int off = 32; off > 0; off >>= 1) {
        lmin = fminf(lmin, __shfl_down(lmin, off));
        lmax = fmaxf(lmax, __shfl_down(lmax, off));
        lsum += __shfl_down(lsum, off);
    }
    __shared__ float smn[4], smx[4], ssm[4];
    __shared__ unsigned sfb[4];
    if (lane == 0) {
        smn[w] = lmin;
        smx[w] = lmax;
        ssm[w] = lsum;
        sfb[w] = any;
    }
    __syncthreads();
    if (tid == 0) {
        unsigned a = sfb[0] | sfb[1] | sfb[2] | sfb[3];
        float bmn = smn[0], bmx = smx[0], bsm = ssm[0];
#pragma unroll
        for (int i = 1; i < 4; ++i) {
            bmn = fminf(bmn, smn[i]);
            bmx = fmaxf(bmx, smx[i]);
            bsm += ssm[i];
        }
        if (a) atomicAdd(cntOut, 1u);
        atomicMin(&omin[s], __float_as_uint(bmn));
        if (bmx > 0.f) atomicMax(&omax[s], __float_as_uint(bmx));
        if (bsm > 0.f) atomicAdd(&osum[s], (double)bsm);
    }
}

// ---------------- iterations 1..9 (chunk-sparse tail) ----------------
// Block = 16-row tile, 4 waves; wave w owns rows [ry+4w, ry+4w+4); lane owns
// 16 px (chunk = 4 lanes = 64 px). Loads/stores gated by per-row chunk masks.
__global__ __launch_bounds__(256, 4) void convt_kernel(
    const float* __restrict__ in, float* __restrict__ out,
    const unsigned* __restrict__ Fprev, unsigned* __restrict__ Fout,
    const unsigned* __restrict__ cntPrev, unsigned* __restrict__ cntOut,
    const unsigned* __restrict__ pmin, const unsigned* __restrict__ pmax,
    unsigned* __restrict__ omin, unsigned* __restrict__ omax,
    double* __restrict__ osum) {
    if (*cntPrev == 0u) return;  // field died: absorbing state

    int blk = blockIdx.x;
    blk = (blk & 7) * (NTILES >> 3) + (blk >> 3);
    const int s = blk >> 6, ty = blk & 63, ry = ty << 4;
    const int tid = threadIdx.x, lane = tid & 63, w = tid >> 6;
    const int xb = lane << 4;
    const size_t sbase = (size_t)s * NPIX;

    __shared__ unsigned sM[18];  // masks of rows ry-1 .. ry+16
    __shared__ int sSkip;
    if (tid < 18) {
        const int yy = ry - 1 + tid;
        sM[tid] = (yy >= 0 && yy < HH) ? Fprev[(s << 10) + yy] : 0u;
    }
    __syncthreads();
    if (tid == 0) {
        unsigned a = 0;
#pragma unroll
        for (int i = 0; i < 18; ++i) a |= sM[i];
        sSkip = (a == 0u);
    }
    __syncthreads();
    if (sSkip) {  // nothing in reach: tile output exactly zero
        if (tid == 0) atomicMin(&omin[s], 0u);
        return;
    }

    float a = 1.f, cc = 0.f;
    {
        const float mn = __uint_as_float(pmin[s]);
        const float mx = __uint_as_float(pmax[s]);
        const float ptp = mx - mn;
        if (ptp > 0.f) { a = 1.f / ptp; cc = mn; }
    }

    const int r0 = w << 2;
    float A[16], B[16], C[16], O[16];
    const int ck = lane >> 2;                         // chunk 0..15
    const int cbit = ((ck >> 2) << 3) + (ck & 3);     // its uint bit position

    auto loadRow = [&](int y, float* V) {
        const unsigned mask = sM[y - ry + 1];
        if (!((mask >> cbit) & 1u)) {
#pragma unroll
            for (int j = 0; j < 16; ++j) V[j] = 0.f;
            return;
        }
        const size_t idx = sbase + (size_t)y * WW + xb;
#pragma unroll
        for (int q = 0; q < 4; ++q) {
            const float4 v = ld4f(in + idx + 4 * q);
            V[4 * q + 0] = v.x;
            V[4 * q + 1] = v.y;
            V[4 * q + 2] = v.z;
            V[4 * q + 3] = v.w;
        }
    };

    loadRow(ry + r0 - 1, A);
    loadRow(ry + r0, B);

    float lmin = 3.4e38f, lmax = 0.f, lsum = 0.f;
    unsigned blockAny = 0u;

#pragma unroll
    for (int r = 0; r < 4; ++r) {
        const int y = ry + r0 + r;
        loadRow(y + 1, C);
        const int mi = r0 + r + 1;  // sM index of row y
        const bool act = (sM[mi - 1] | sM[mi] | sM[mi + 1]) != 0;
        if (act) {
            float lfe = __shfl_up(B[15], 1);
            if (lane == 0) lfe = 0.f;
            float rte = __shfl_down(B[0], 1);
            if (lane == 63) rte = 0.f;
            const float vert =
                1.f + (y > 0 ? 1.f : 0.f) + (y < HH - 1 ? 1.f : 0.f);
            bool nz = false;
#pragma unroll
            for (int j = 0; j < 16; ++j) {
                const float lf = (j == 0) ? lfe : B[j - 1];
                const float rt = (j == 15) ? rte : B[j + 1];
                const float conv = 0.2f * (A[j] + C[j] + B[j] + lf + rt);
                const int x = xb + j;
                const float kf = 0.2f * (vert + (x > 0 ? 1.f : 0.f) +
                                         (x < WW - 1 ? 1.f : 0.f));
                const float dil = (conv - cc * kf) * a;
                const float er = fmaxf(dil - 0.5f, 0.f);
                O[j] = er;
                lmin = fminf(lmin, er);
                lmax = fmaxf(lmax, er);
                lsum += er;
                nz = nz || (er > 0.f);
            }
            const unsigned long long bal = __ballot(nz);
            // store lane's 16 px iff its chunk (4 lanes) has a nonzero
            if (((bal >> (ck << 2)) & 0xFull) != 0ull) {
                const size_t oidx = sbase + (size_t)y * WW + xb;
#pragma unroll
                for (int q = 0; q < 4; ++q)
                    *reinterpret_cast<float4*>(out + oidx + 4 * q) =
                        make_float4(O[4 * q], O[4 * q + 1], O[4 * q + 2],
                                    O[4 * q + 3]);
            }
            unsigned rm = 0;
#pragma unroll
            for (int c = 0; c < 16; ++c)
                if ((bal >> (c << 2)) & 0xFull)
                    rm |= 1u << (((c >> 2) << 3) + (c & 3));
            if (lane == 0) Fout[(s << 10) + y] = rm;  // owned row
            blockAny |= rm;
        } else {
            lmin = fminf(lmin, 0.f);  // row is exactly zero (mask pre-zeroed)
        }
#pragma unroll
        for (int j = 0; j < 16; ++j) {
            A[j] = B[j];
            B[j] = C[j];
        }
    }

#pragma unroll
    for (int off = 32; off > 0; off >>= 1) {
        lmin = fminf(lmin, __shfl_down(lmin, off));
        lmax = fmaxf(lmax, __shfl_down(lmax, off));
        lsum += __shfl_down(lsum, off);
    }
    __shared__ float smn[4], smx[4], ssm[4];
    __shared__ unsigned sfb[4];
    if (lane == 0) {
        smn[w] = lmin;
        smx[w] = lmax;
        ssm[w] = lsum;
        sfb[w] = blockAny;
    }
    __syncthreads();
    if (tid == 0) {
        const unsigned anyb = sfb[0] | sfb[1] | sfb[2] | sfb[3];
        float bmn = smn[0], bmx = smx[0], bsm = ssm[0];
#pragma unroll
        for (int i = 1; i < 4; ++i) {
            bmn = fminf(bmn, smn[i]);
            bmx = fmaxf(bmx, smx[i]);
            bsm += ssm[i];
        }
        if (anyb) atomicAdd(cntOut, 1u);
        atomicMin(&omin[s], __float_as_uint(bmn));
        if (bmx > 0.f) atomicMax(&omax[s], __float_as_uint(bmx));
        if (bsm > 0.f) atomicAdd(&osum[s], (double)bsm);
    }
}

__global__ void init_kernel(unsigned* __restrict__ minb,
                            unsigned* __restrict__ maxb,
                            double* __restrict__ sums,
                            unsigned* __restrict__ F,
                            unsigned* __restrict__ cnt) {
    const int i = blockIdx.x * blockDim.x + threadIdx.x;
    if (i < NEROS * BATCH) {
        minb[i] = 0x7f800000u;  // +inf
        maxb[i] = 0u;
        sums[i] = 0.0;
    }
    if (i < NEROS * BATCH * FRPS) F[i] = 0u;
    if (i < NEROS) cnt[i] = 0u;
}

__global__ void final_kernel(const unsigned* __restrict__ minb,
                             const unsigned* __restrict__ maxb,
                             const double* __restrict__ sums,
                             float* __restrict__ out) {
    const int s = threadIdx.x;
    double tot = 0.0;
    if (s < BATCH) {
        for (int k = 0; k < NEROS; ++k) {
            const float mn = __uint_as_float(minb[k * BATCH + s]);
            const float mx = __uint_as_float(maxb[k * BATCH + s]);
            const double sm = sums[k * BATCH + s];
            const float ptp = mx - mn;
            double v;
            if (ptp > 0.f)
                v = (sm - (double)NPIX * (double)mn) / (double)ptp;
            else
                v = sm;
            tot += (double)((k + 1) * (k + 1)) * v;
        }
    }
#pragma unroll
    for (int off = 32; off > 0; off >>= 1) tot += __shfl_down(tot, off);
    if (s == 0) out[0] = (float)(tot / ((double)BATCH * (double)NPIX));
}

extern "C" void kernel_launch(void* const* d_in, const int* in_sizes, int n_in,
                              void* d_out, int out_size, void* d_ws,
                              size_t ws_size, hipStream_t stream) {
    const float* pred = (const float*)d_in[0];
    const float* tgt = (const float*)d_in[1];
    float* out = (float*)d_out;

    float* buf0 = (float*)d_ws;
    float* buf1 = buf0 + (size_t)BATCH * NPIX;
    unsigned* minb = (unsigned*)(buf1 + (size_t)BATCH * NPIX);
    unsigned* maxb = minb + NEROS * BATCH;
    double* sums = (double*)(maxb + NEROS * BATCH);
    unsigned* F = (unsigned*)(sums + NEROS * BATCH);
    unsigned* cnt = F + (size_t)NEROS * BATCH * FRPS;

    init_kernel<<<1280, 256, 0, stream>>>(minb, maxb, sums, F, cnt);

    conv0_kernel<<<NB0, 256, 0, stream>>>(pred, tgt, buf0, F, &cnt[0], minb,
                                          maxb, sums);

    float* bufs[2] = {buf0, buf1};
    for (int k = 1; k < NEROS; ++k) {
        const float* src = bufs[(k - 1) & 1];
        float* dst = bufs[k & 1];
        convt_kernel<<<NTILES, 256, 0, stream>>>(
            src, dst, F + (size_t)(k - 1) * BATCH * FRPS,
            F + (size_t)k * BATCH * FRPS, &cnt[k - 1], &cnt[k],
            minb + (size_t)(k - 1) * BATCH, maxb + (size_t)(k - 1) * BATCH,
            minb + (size_t)k * BATCH, maxb + (size_t)k * BATCH,
            sums + (size_t)k * BATCH);
    }

    final_kernel<<<1, 64, 0, stream>>>(minb, maxb, sums, out);
}